// Round 4
// baseline (385.279 us; speedup 1.0000x reference)
//
#include <hip/hip_runtime.h>
#include <stdint.h>

#define B_DIM 4
#define L_DIM 512
#define D_DIM 768
#define S_DIM 4096
#define DFF_DIM 3072
#define M_DIM (B_DIM * S_DIM)   // 16384

typedef unsigned short ushort_t;
typedef __attribute__((ext_vector_type(8))) short short8;
typedef __attribute__((ext_vector_type(4))) short short4v;
typedef __attribute__((ext_vector_type(4))) float floatx4;

// round-to-nearest-even fp32 -> bf16 bits
__device__ __forceinline__ ushort_t f2bf(float x) {
  unsigned int u = __float_as_uint(x);
  u += 0x7FFFu + ((u >> 16) & 1u);
  return (ushort_t)(u >> 16);
}

// async 16B global->LDS (wave-uniform base + lane*16 dest required)
__device__ __forceinline__ void load_lds16(const ushort_t* g, ushort_t* lds) {
  __builtin_amdgcn_global_load_lds(
      (const __attribute__((address_space(1))) unsigned int*)g,
      (__attribute__((address_space(3))) unsigned int*)lds, 16, 0, 0);
}

// ---------------------------------------------------------------------------
// Fused prep: W1 transpose | W2 transpose | span gather+mean, one launch.
// Span gather vectorized: float4 loads, short4 bf16 stores (G13).
// ---------------------------------------------------------------------------
__device__ __forceinline__ void transpose_body(const float* __restrict__ in,
                                               ushort_t* __restrict__ out,
                                               int K, int N, int kb, int nb) {
  __shared__ float tile[32][33];
  const int k0 = kb * 32;
  const int n0 = nb * 32;
  const int tx = threadIdx.x & 31;
  const int ty = threadIdx.x >> 5;  // 0..7
#pragma unroll
  for (int r = 0; r < 32; r += 8)
    tile[ty + r][tx] = in[(long)(k0 + ty + r) * N + n0 + tx];
  __syncthreads();
#pragma unroll
  for (int r = 0; r < 32; r += 8)
    out[(long)(n0 + ty + r) * K + k0 + tx] = f2bf(tile[tx][ty + r]);
}

__device__ __forceinline__ void span_body(const float* __restrict__ h,
                                          const int* __restrict__ span_idx,
                                          ushort_t* __restrict__ A, int blk) {
  const int wave = threadIdx.x >> 6;
  const int lane = threadIdx.x & 63;
  const int span = blk * 4 + wave;  // 0..M-1
  const int b = span >> 12;         // span / S_DIM
  const int start = span_idx[span * 2 + 0];
  const int end   = span_idx[span * 2 + 1];
  const float inv = 1.0f / (float)(end - start + 1);
  const floatx4* hb =
      (const floatx4*)(h + ((long)b * L_DIM + start) * D_DIM) + lane;
  floatx4 a[3];
#pragma unroll
  for (int c = 0; c < 3; ++c) a[c] = (floatx4)0.0f;
  for (int p = start; p <= end; ++p) {
#pragma unroll
    for (int c = 0; c < 3; ++c) a[c] += hb[c * 64];
    hb += 192;  // 768 floats / 4
  }
  short4v* o = (short4v*)(A + (long)span * D_DIM) + lane;
#pragma unroll
  for (int c = 0; c < 3; ++c) {
    short4v s;
#pragma unroll
    for (int e = 0; e < 4; ++e) s[e] = (short)f2bf(a[c][e] * inv);
    o[c * 64] = s;
  }
}

__global__ __launch_bounds__(256)
void prep(const float* __restrict__ W1, ushort_t* __restrict__ W1T,
          const float* __restrict__ W2, ushort_t* __restrict__ W2T,
          const float* __restrict__ h, const int* __restrict__ span_idx,
          ushort_t* __restrict__ A) {
  const int blk = blockIdx.x;
  if (blk < 2304) {
    transpose_body(W1, W1T, D_DIM, DFF_DIM, blk % 24, blk / 24);
  } else if (blk < 4608) {
    const int b = blk - 2304;
    transpose_body(W2, W2T, DFF_DIM, D_DIM, b % 96, b / 96);
  } else {
    span_body(h, span_idx, A, blk - 4608);
  }
}

// ---------------------------------------------------------------------------
// GEMM1, barrier-free: Hm[M][DFF] = relu(A[M][768] * W1T[DFF][768]^T + b1)
// - Full-K W1T panel (96 cols x 768 K = 147 KB) resident in LDS, staged ONCE
//   per block (chunk-XOR swizzled via pre-swizzled global source, rule 21).
// - A-fragments stream straight from global into VGPRs: per load, 64 lanes
//   cover 16 rows x 64 B contiguous = fully coalesced; A is L2-resident
//   (XCD-grouped bm: 8 panels x 384 KB = 3 MB per XCD L2).
// - ZERO barriers in the K-loop: no lockstep, no vmcnt drains. 1-deep
//   register pipeline (prefetch kstep+1 while MFMAing kstep); compiler
//   inserts counted waits. MFMA-bound by construction:
//   24 MFMA x 19.4 cy = 466 cy/SIMD/kstep vs A-traffic 34 B/cy < L2 56.
// Tile: 256M x 96N, 8 waves (4M x 2N), wave-tile 64 x 48 (4 x 3 frags).
// ---------------------------------------------------------------------------
__global__ __launch_bounds__(512, 2)
void gemm1_bres(const ushort_t* __restrict__ A, const ushort_t* __restrict__ Bt,
                const float* __restrict__ bias, ushort_t* __restrict__ C) {
  __shared__ ushort_t Bs[96 * 768];  // 147456 B

  const int tid  = threadIdx.x;
  const int lane = tid & 63;
  const int l16  = lane & 15;
  const int quad = lane >> 4;
  const int wave = tid >> 6;
  const int wr   = wave >> 1;  // 0..3 (M quarter, 64 rows)
  const int wc   = wave & 1;   // 0..1 (N half, 48 cols)

  // XCD-grouped swizzle: 2048 blocks = 8 xcd x (8 bm x 32 bn). Bijective.
  const int id  = blockIdx.x;
  const int xcd = id & 7;
  const int loc = id >> 3;
  const int bm  = xcd * 8 + (loc & 7);  // 0..63
  const int bn  = loc >> 3;             // 0..31

  // ---- stage B panel once: LDS row t (= output col) holds global k-chunk
  // c ^ (t&7) at slot c. Linear LDS dest (s*16B), swizzle on global source.
  {
    const ushort_t* src = Bt + (long)bn * 96 * 768;
#pragma unroll
    for (int i = 0; i < 18; ++i) {
      const int s = tid + i * 512;       // 0..9215 (= 96 rows * 96 chunks)
      const int row = s / 96;
      const int chunk = s - row * 96;
      const int gchunk = chunk ^ (row & 7);
      load_lds16(src + (long)row * 768 + gchunk * 8, &Bs[0] + s * 8);
    }
  }

  // A-frag addressing: row = bm*256 + wr*64 + mg*16 + l16, k-bytes: quad*16
  const ushort_t* gA =
      A + (long)(bm * 256 + wr * 64 + l16) * 768 + quad * 8;
  // B-frag addressing: t = wc*48 + j*16 + l16; elem = t*768 + ((k*4+quad)^(t&7))*8
  const int t0 = wc * 48 + l16;

  floatx4 acc[4][3];
#pragma unroll
  for (int m = 0; m < 4; ++m)
#pragma unroll
    for (int j = 0; j < 3; ++j) acc[m][j] = (floatx4)0.0f;

  __syncthreads();  // one-time: B panel staged (drains stage DMA)

  short8 aA[4], aB[4], bA[3], bB[3];
  // preload kstep 0
#pragma unroll
  for (int m = 0; m < 4; ++m)
    aA[m] = *(const short8*)(gA + (long)m * (16 * 768));
#pragma unroll
  for (int j = 0; j < 3; ++j) {
    const int t = t0 + j * 16;
    bA[j] = *(const short8*)(&Bs[0] + (long)t * 768 + ((quad) ^ (t & 7)) * 8);
  }

#pragma unroll
  for (int k = 0; k < 24; ++k) {
    if (k + 1 < 24) {  // prefetch kstep k+1 (regs; compiler counts the waits)
      const long ko = (long)(k + 1) * 32;
#pragma unroll
      for (int m = 0; m < 4; ++m)
        aB[m] = *(const short8*)(gA + (long)m * (16 * 768) + ko);
#pragma unroll
      for (int j = 0; j < 3; ++j) {
        const int t = t0 + j * 16;
        bB[j] = *(const short8*)(&Bs[0] + (long)t * 768 +
                                 (((k + 1) * 4 + quad) ^ (t & 7)) * 8);
      }
    }
#pragma unroll
    for (int m = 0; m < 4; ++m)
#pragma unroll
      for (int j = 0; j < 3; ++j)
        acc[m][j] = __builtin_amdgcn_mfma_f32_16x16x32_bf16(aA[m], bA[j],
                                                            acc[m][j], 0, 0, 0);
    // rotate (renamed away by full unroll -- static indexing, rule 20)
#pragma unroll
    for (int m = 0; m < 4; ++m) aA[m] = aB[m];
#pragma unroll
    for (int j = 0; j < 3; ++j) bA[j] = bB[j];
  }

  // epilogue: C/D layout col = l16, row = quad*4 + r
  const long rowbase = (long)bm * 256 + wr * 64 + quad * 4;
  const int  colbase = bn * 96 + wc * 48 + l16;
#pragma unroll
  for (int j = 0; j < 3; ++j) {
    const int col = colbase + j * 16;
    const float bv = bias[col];
#pragma unroll
    for (int m = 0; m < 4; ++m) {
      const long row0 = rowbase + m * 16;
#pragma unroll
      for (int r = 0; r < 4; ++r) {
        float v = acc[m][j][r] + bv;
        v = v > 0.0f ? v : 0.0f;
        C[(row0 + r) * DFF_DIM + col] = f2bf(v);
      }
    }
  }
}

// ---------------------------------------------------------------------------
// GEMM2: round-0 PROVEN kernel, verbatim (111.4 us measured).
// 128x128 tile, BK=32, double-buffered LDS, chunk-XOR swizzle.
// MODE 1: out = acc + bias[col] -> fp32
// ---------------------------------------------------------------------------
template <int MODE>
__global__ __launch_bounds__(256)
void gemm_bt(const ushort_t* __restrict__ A, const ushort_t* __restrict__ Bt,
             const float* __restrict__ bias, void* __restrict__ Cv,
             int M, int N, int K) {
  __shared__ ushort_t As[2][128 * 32];
  __shared__ ushort_t Bs[2][128 * 32];

  const int tid  = threadIdx.x;
  const int lane = tid & 63;
  const int wave = tid >> 6;
  const int l16  = lane & 15;
  const int quad = lane >> 4;

  const int bm = blockIdx.x;
  const int bn = blockIdx.y;

  const int wm = (wave & 1) * 64;
  const int wn = (wave >> 1) * 64;

  const int swz  = (l16 & 3) ^ ((l16 >> 2) & 3);
  const int coff = (quad ^ swz) * 8;

  floatx4 acc[4][4];
#pragma unroll
  for (int i = 0; i < 4; ++i)
#pragma unroll
    for (int j = 0; j < 4; ++j)
      acc[i][j] = (floatx4)0.0f;

  const int s0 = tid, s1 = tid + 256;
  const int r0 = s0 >> 2, r1 = s1 >> 2;
  const int c0 = (s0 & 3) ^ (r0 & 3) ^ ((r0 >> 2) & 3);
  const int c1 = (s1 & 3) ^ (r1 & 3) ^ ((r1 >> 2) & 3);
  const ushort_t* gA0 = A + (long)(bm * 128 + r0) * K + c0 * 8;
  const ushort_t* gA1 = A + (long)(bm * 128 + r1) * K + c1 * 8;
  const ushort_t* gB0 = Bt + (long)(bn * 128 + r0) * K + c0 * 8;
  const ushort_t* gB1 = Bt + (long)(bn * 128 + r1) * K + c1 * 8;

  const int nk = K >> 5;

  load_lds16(gA0, &As[0][0] + s0 * 8);
  load_lds16(gA1, &As[0][0] + s1 * 8);
  load_lds16(gB0, &Bs[0][0] + s0 * 8);
  load_lds16(gB1, &Bs[0][0] + s1 * 8);

  for (int k = 0; k < nk; ++k) {
    const int cur = k & 1;
    const int nxt = cur ^ 1;
    __syncthreads();

    if (k + 1 < nk) {
      const int off = (k + 1) * 32;
      load_lds16(gA0 + off, &As[nxt][0] + s0 * 8);
      load_lds16(gA1 + off, &As[nxt][0] + s1 * 8);
      load_lds16(gB0 + off, &Bs[nxt][0] + s0 * 8);
      load_lds16(gB1 + off, &Bs[nxt][0] + s1 * 8);
    }

    short8 af[4], bf[4];
#pragma unroll
    for (int i = 0; i < 4; ++i)
      af[i] = *(const short8*)(&As[cur][0] + (wm + i * 16 + l16) * 32 + coff);
#pragma unroll
    for (int j = 0; j < 4; ++j)
      bf[j] = *(const short8*)(&Bs[cur][0] + (wn + j * 16 + l16) * 32 + coff);
#pragma unroll
    for (int i = 0; i < 4; ++i)
#pragma unroll
      for (int j = 0; j < 4; ++j)
        acc[i][j] = __builtin_amdgcn_mfma_f32_16x16x32_bf16(af[i], bf[j], acc[i][j], 0, 0, 0);
  }

#pragma unroll
  for (int i = 0; i < 4; ++i) {
#pragma unroll
    for (int j = 0; j < 4; ++j) {
      const int col = bn * 128 + wn + j * 16 + l16;
      const float bv = bias[col];
      const int row0 = bm * 128 + wm + i * 16 + quad * 4;
#pragma unroll
      for (int r = 0; r < 4; ++r) {
        float v = acc[i][j][r] + bv;
        if (MODE == 0) {
          v = v > 0.0f ? v : 0.0f;
          ((ushort_t*)Cv)[(long)(row0 + r) * N + col] = f2bf(v);
        } else {
          ((float*)Cv)[(long)(row0 + r) * N + col] = v;
        }
      }
    }
  }
}

extern "C" void kernel_launch(void* const* d_in, const int* in_sizes, int n_in,
                              void* d_out, int out_size, void* d_ws, size_t ws_size,
                              hipStream_t stream) {
  const float* h        = (const float*)d_in[0];
  const int*   span_idx = (const int*)d_in[1];
  const float* W1       = (const float*)d_in[2];
  const float* b1       = (const float*)d_in[3];
  const float* W2       = (const float*)d_in[4];
  const float* b2       = (const float*)d_in[5];
  float* out = (float*)d_out;

  // workspace layout (bf16 elements): A | W1T | W2T | Hmid
  ushort_t* A   = (ushort_t*)d_ws;
  ushort_t* W1T = A + (size_t)M_DIM * D_DIM;
  ushort_t* W2T = W1T + (size_t)DFF_DIM * D_DIM;
  ushort_t* Hm  = W2T + (size_t)D_DIM * DFF_DIM;

  // fused prep: both weight transposes + span gather in one launch
  prep<<<2304 + 2304 + M_DIM / 4, 256, 0, stream>>>(W1, W1T, W2, W2T, h, span_idx, A);

  // GEMM1: barrier-free B-resident kernel (256x96 tiles, 64 bm x 32 bn)
  gemm1_bres<<<dim3(2048), 512, 0, stream>>>(A, W1T, b1, Hm);

  // GEMM2: Hmid (M x DFF) * W2 (DFF x D) + b2 -> out fp32 (M x D)  [proven]
  gemm_bt<1><<<dim3(M_DIM / 128, D_DIM / 128), 256, 0, stream>>>(
      Hm, W2T, b2, out, M_DIM, D_DIM, DFF_DIM);
}

// Round 5
// 275.109 us; speedup vs baseline: 1.4005x; 1.4005x over previous
//
#include <hip/hip_runtime.h>
#include <stdint.h>

#define B_DIM 4
#define L_DIM 512
#define D_DIM 768
#define S_DIM 4096
#define DFF_DIM 3072
#define M_DIM (B_DIM * S_DIM)   // 16384

typedef unsigned short ushort_t;
typedef __attribute__((ext_vector_type(8))) short short8;
typedef __attribute__((ext_vector_type(4))) short short4v;
typedef __attribute__((ext_vector_type(4))) float floatx4;

// round-to-nearest-even fp32 -> bf16 bits
__device__ __forceinline__ ushort_t f2bf(float x) {
  unsigned int u = __float_as_uint(x);
  u += 0x7FFFu + ((u >> 16) & 1u);
  return (ushort_t)(u >> 16);
}

// async 16B global->LDS (lane-contiguous dest)
__device__ __forceinline__ void load_lds16(const ushort_t* g, ushort_t* lds) {
  __builtin_amdgcn_global_load_lds(
      (const __attribute__((address_space(1))) unsigned int*)g,
      (__attribute__((address_space(3))) unsigned int*)lds, 16, 0, 0);
}

// single-barrier phase fence (no memory clobber -> no compiler vmcnt drain)
#define PIN() __builtin_amdgcn_sched_barrier(0)
#define BAR()                                  \
  do {                                         \
    PIN();                                     \
    __builtin_amdgcn_s_barrier();              \
    PIN();                                     \
  } while (0)
#define WAIT_LGKM0()                           \
  do {                                         \
    asm volatile("s_waitcnt lgkmcnt(0)");      \
    PIN();                                     \
  } while (0)
#define WAIT_VM(n)                             \
  do {                                         \
    asm volatile("s_waitcnt vmcnt(" #n ")");   \
    PIN();                                     \
  } while (0)

// ---------------------------------------------------------------------------
// Fused prep: W1 transpose | W2 transpose | span gather+mean (float4 loads).
// ---------------------------------------------------------------------------
__device__ __forceinline__ void transpose_body(const float* __restrict__ in,
                                               ushort_t* __restrict__ out,
                                               int K, int N, int kb, int nb) {
  __shared__ float tile[32][33];
  const int k0 = kb * 32;
  const int n0 = nb * 32;
  const int tx = threadIdx.x & 31;
  const int ty = threadIdx.x >> 5;  // 0..7
#pragma unroll
  for (int r = 0; r < 32; r += 8)
    tile[ty + r][tx] = in[(long)(k0 + ty + r) * N + n0 + tx];
  __syncthreads();
#pragma unroll
  for (int r = 0; r < 32; r += 8)
    out[(long)(n0 + ty + r) * K + k0 + tx] = f2bf(tile[tx][ty + r]);
}

__device__ __forceinline__ void span_body(const float* __restrict__ h,
                                          const int* __restrict__ span_idx,
                                          ushort_t* __restrict__ A, int blk) {
  const int wave = threadIdx.x >> 6;
  const int lane = threadIdx.x & 63;
  const int span = blk * 4 + wave;  // 0..M-1
  const int b = span >> 12;
  const int start = span_idx[span * 2 + 0];
  const int end   = span_idx[span * 2 + 1];
  const float inv = 1.0f / (float)(end - start + 1);
  const floatx4* hb =
      (const floatx4*)(h + ((long)b * L_DIM + start) * D_DIM) + lane;
  floatx4 a[3];
#pragma unroll
  for (int c = 0; c < 3; ++c) a[c] = (floatx4)0.0f;
  for (int p = start; p <= end; ++p) {
#pragma unroll
    for (int c = 0; c < 3; ++c) a[c] += hb[c * 64];
    hb += 192;
  }
  short4v* o = (short4v*)(A + (long)span * D_DIM) + lane;
#pragma unroll
  for (int c = 0; c < 3; ++c) {
    short4v s;
#pragma unroll
    for (int e = 0; e < 4; ++e) s[e] = (short)f2bf(a[c][e] * inv);
    o[c * 64] = s;
  }
}

__global__ __launch_bounds__(256)
void prep(const float* __restrict__ W1, ushort_t* __restrict__ W1T,
          const float* __restrict__ W2, ushort_t* __restrict__ W2T,
          const float* __restrict__ h, const int* __restrict__ span_idx,
          ushort_t* __restrict__ A) {
  const int blk = blockIdx.x;
  if (blk < 2304) {
    transpose_body(W1, W1T, D_DIM, DFF_DIM, blk % 24, blk / 24);
  } else if (blk < 4608) {
    const int b = blk - 2304;
    transpose_body(W2, W2T, DFF_DIM, D_DIM, b % 96, b / 96);
  } else {
    span_body(h, span_idx, A, blk - 4608);
  }
}

// ---------------------------------------------------------------------------
// GEMM1 single-barrier pipelined: Hm = relu(A[16384][768] * W1T[3072][768]^T + b1)
// Tile 128(M) x 256(N), BK=64, nk=12. 8 waves (2M x 4N), wave-tile 64x64.
// TRIPLE-buffered LDS (144 KB): tile k reads buf k%3 while staging tile k+2
// into buf (k+2)%3 -- staging runs TWO tiles ahead so the steady-state gate
// is vmcnt(6) (this tile's 6 loads in flight), never 0 until the tail.
// ONE barrier per phase (m201): ds_read(p) -> stage -> BAR -> lgkm0 ->
// prio1 MFMA prio0 -> [next phase ds_reads]. Fast waves run ahead into
// phase p+1's ds_reads/staging while slow waves MFMA phase p = the
// role-split overlap the double-barrier ports destroyed.
// Race-freedom:
//  WAR: buf (k+2)%3 was last ds_read in tile k-1 Ph2; its readers' lgkm0
//       precedes barrier(k-1,Ph3); the overwrite is issued after that
//       barrier -> >=1 barrier separation.
//  RAW: tile k+1's 6 loads (issued in tile k-1) are all older than the 6
//       outstanding at tile k Ph3's vmcnt(6), which precedes the barrier
//       before tile k+1's first ds_read.
// Chunk-XOR-8 LDS swizzle on global source + ds_read addr (R1-3: 0 conflicts).
// ---------------------------------------------------------------------------
__global__ __launch_bounds__(512, 2)
void gemm1_p3(const ushort_t* __restrict__ A, const ushort_t* __restrict__ Bt,
              const float* __restrict__ bias, ushort_t* __restrict__ C) {
  __shared__ ushort_t As[3][128 * 64];  // 49152 B
  __shared__ ushort_t Bs[3][256 * 64];  // 98304 B

  const int tid  = threadIdx.x;
  const int lane = tid & 63;
  const int l16  = lane & 15;
  const int quad = lane >> 4;
  const int wave = tid >> 6;
  const int wr   = wave >> 2;  // 0..1 (M half, 64 rows)
  const int wc   = wave & 3;   // 0..3 (N quarter, 64 cols)

  const int bm = blockIdx.x;   // 0..127
  const int bn = blockIdx.y;   // 0..11

  // staging: seg s -> LDS row s>>3, slot s&7; global chunk = slot ^ (row&7)
  const int srow = tid >> 3;   // 0..63
  const int gch  = (tid & 7) ^ (srow & 7);
  const ushort_t* gA = A  + (long)(bm * 128 + srow) * 768 + gch * 8;
  const ushort_t* gB = Bt + (long)(bn * 256 + srow) * 768 + gch * 8;
  const long r64 = (long)768 * 64;  // 64-row stride (XOR pattern repeats mod 8)

  auto STAGE_A = [&](int buf, int kt) {   // A rows 0..127 (2 loads)
    const long ko = (long)kt * 64;
    ushort_t* la = &As[buf][0] + tid * 8;
    load_lds16(gA + ko,       la);
    load_lds16(gA + ko + r64, la + 4096);
  };
  auto STAGE_B01 = [&](int buf, int kt) { // B rows 0..127
    const long ko = (long)kt * 64;
    ushort_t* lb = &Bs[buf][0] + tid * 8;
    load_lds16(gB + ko,       lb);
    load_lds16(gB + ko + r64, lb + 4096);
  };
  auto STAGE_B23 = [&](int buf, int kt) { // B rows 128..255
    const long ko = (long)kt * 64;
    ushort_t* lb = &Bs[buf][0] + tid * 8;
    load_lds16(gB + ko + 2 * r64, lb + 8192);
    load_lds16(gB + ko + 3 * r64, lb + 12288);
  };

  // fragment reads: elem = row*64 + (kchunk ^ (row&7))*8 ; row&7 == l16&7
  const int arow0 = (wr * 64 + l16) * 64;
  const int brow0 = (wc * 64 + l16) * 64;
  const int cx0 = ((quad)     ^ (l16 & 7)) << 3;  // kstep 0
  const int cx1 = ((quad + 4) ^ (l16 & 7)) << 3;  // kstep 1

  floatx4 acc[4][4];
#pragma unroll
  for (int i = 0; i < 4; ++i)
#pragma unroll
    for (int j = 0; j < 4; ++j) acc[i][j] = (floatx4)0.0f;

  const int nk = 12;  // 768 / 64

  // prologue: stage tiles 0 and 1; gate tile 0 (tile 1's 6 stay in flight)
  STAGE_A(0, 0); STAGE_B01(0, 0); STAGE_B23(0, 0);
  STAGE_A(1, 1); STAGE_B01(1, 1); STAGE_B23(1, 1);
  WAIT_VM(6);
  BAR();

  short8 a0[2][2], a2[2][2], b0[2][2], b2[2][2];  // [frag][kstep]
  int cur = 0;

  for (int k = 0; k < nk; ++k) {
    const int s2 = (cur + 2 >= 3) ? cur - 1 : cur + 2;  // (k+2)%3
    const ushort_t* Ac = &As[cur][0];
    const ushort_t* Bc = &Bs[cur][0];
    const bool pf = (k + 2 < nk);

    // ---- Ph0: ds a0(i=0,1) + b0(j=0,1); stage A(k+2) | MFMA q00 ----------
#pragma unroll
    for (int i = 0; i < 2; ++i) {
      a0[i][0] = *(const short8*)(Ac + arow0 + i * 1024 + cx0);
      a0[i][1] = *(const short8*)(Ac + arow0 + i * 1024 + cx1);
    }
#pragma unroll
    for (int j = 0; j < 2; ++j) {
      b0[j][0] = *(const short8*)(Bc + brow0 + j * 1024 + cx0);
      b0[j][1] = *(const short8*)(Bc + brow0 + j * 1024 + cx1);
    }
    if (pf) STAGE_A(s2, k + 2);
    BAR();
    WAIT_LGKM0();
    __builtin_amdgcn_s_setprio(1);
#pragma unroll
    for (int i = 0; i < 2; ++i)
#pragma unroll
      for (int j = 0; j < 2; ++j) {
        acc[i][j] = __builtin_amdgcn_mfma_f32_16x16x32_bf16(a0[i][0], b0[j][0], acc[i][j], 0, 0, 0);
        acc[i][j] = __builtin_amdgcn_mfma_f32_16x16x32_bf16(a0[i][1], b0[j][1], acc[i][j], 0, 0, 0);
      }
    __builtin_amdgcn_s_setprio(0);

    // ---- Ph1: ds b2(j=2,3); stage B01(k+2) | MFMA q01 ---------------------
#pragma unroll
    for (int j = 0; j < 2; ++j) {
      b2[j][0] = *(const short8*)(Bc + brow0 + (2 + j) * 1024 + cx0);
      b2[j][1] = *(const short8*)(Bc + brow0 + (2 + j) * 1024 + cx1);
    }
    if (pf) STAGE_B01(s2, k + 2);
    BAR();
    WAIT_LGKM0();
    __builtin_amdgcn_s_setprio(1);
#pragma unroll
    for (int i = 0; i < 2; ++i)
#pragma unroll
      for (int j = 0; j < 2; ++j) {
        acc[i][2 + j] = __builtin_amdgcn_mfma_f32_16x16x32_bf16(a0[i][0], b2[j][0], acc[i][2 + j], 0, 0, 0);
        acc[i][2 + j] = __builtin_amdgcn_mfma_f32_16x16x32_bf16(a0[i][1], b2[j][1], acc[i][2 + j], 0, 0, 0);
      }
    __builtin_amdgcn_s_setprio(0);

    // ---- Ph2: ds a2(i=2,3); stage B23(k+2) | MFMA q11 ---------------------
#pragma unroll
    for (int i = 0; i < 2; ++i) {
      a2[i][0] = *(const short8*)(Ac + arow0 + (2 + i) * 1024 + cx0);
      a2[i][1] = *(const short8*)(Ac + arow0 + (2 + i) * 1024 + cx1);
    }
    if (pf) STAGE_B23(s2, k + 2);
    BAR();
    WAIT_LGKM0();
    __builtin_amdgcn_s_setprio(1);
#pragma unroll
    for (int i = 0; i < 2; ++i)
#pragma unroll
      for (int j = 0; j < 2; ++j) {
        acc[2 + i][2 + j] = __builtin_amdgcn_mfma_f32_16x16x32_bf16(a2[i][0], b2[j][0], acc[2 + i][2 + j], 0, 0, 0);
        acc[2 + i][2 + j] = __builtin_amdgcn_mfma_f32_16x16x32_bf16(a2[i][1], b2[j][1], acc[2 + i][2 + j], 0, 0, 0);
      }
    __builtin_amdgcn_s_setprio(0);

    // ---- Ph3: gate (counted) | BAR | MFMA q10 (regs only) -----------------
    if (pf) {
      WAIT_VM(6);   // tile k+1 fully landed; this tile's 6 stay in flight
    } else {
      WAIT_VM(0);   // tail drain
    }
    BAR();
    __builtin_amdgcn_s_setprio(1);
#pragma unroll
    for (int i = 0; i < 2; ++i)
#pragma unroll
      for (int j = 0; j < 2; ++j) {
        acc[2 + i][j] = __builtin_amdgcn_mfma_f32_16x16x32_bf16(a2[i][0], b0[j][0], acc[2 + i][j], 0, 0, 0);
        acc[2 + i][j] = __builtin_amdgcn_mfma_f32_16x16x32_bf16(a2[i][1], b0[j][1], acc[2 + i][j], 0, 0, 0);
      }
    __builtin_amdgcn_s_setprio(0);

    cur = (cur + 1 >= 3) ? 0 : cur + 1;
  }

  // epilogue: C/D layout col = l16, row = quad*4 + r ; relu -> bf16
  const long rowbase = (long)bm * 128 + wr * 64 + quad * 4;
  const int  colbase = bn * 256 + wc * 64 + l16;
#pragma unroll
  for (int j = 0; j < 4; ++j) {
    const int col = colbase + j * 16;
    const float bv = bias[col];
#pragma unroll
    for (int i = 0; i < 4; ++i) {
      const long row0 = rowbase + i * 16;
#pragma unroll
      for (int r = 0; r < 4; ++r) {
        float v = acc[i][j][r] + bv;
        v = v > 0.0f ? v : 0.0f;
        C[(row0 + r) * DFF_DIM + col] = f2bf(v);
      }
    }
  }
}

// ---------------------------------------------------------------------------
// GEMM2: round-0 PROVEN kernel, verbatim (111.4 us measured).
// ---------------------------------------------------------------------------
template <int MODE>
__global__ __launch_bounds__(256)
void gemm_bt(const ushort_t* __restrict__ A, const ushort_t* __restrict__ Bt,
             const float* __restrict__ bias, void* __restrict__ Cv,
             int M, int N, int K) {
  __shared__ ushort_t As[2][128 * 32];
  __shared__ ushort_t Bs[2][128 * 32];

  const int tid  = threadIdx.x;
  const int lane = tid & 63;
  const int wave = tid >> 6;
  const int l16  = lane & 15;
  const int quad = lane >> 4;

  const int bm = blockIdx.x;
  const int bn = blockIdx.y;

  const int wm = (wave & 1) * 64;
  const int wn = (wave >> 1) * 64;

  const int swz  = (l16 & 3) ^ ((l16 >> 2) & 3);
  const int coff = (quad ^ swz) * 8;

  floatx4 acc[4][4];
#pragma unroll
  for (int i = 0; i < 4; ++i)
#pragma unroll
    for (int j = 0; j < 4; ++j)
      acc[i][j] = (floatx4)0.0f;

  const int s0 = tid, s1 = tid + 256;
  const int r0 = s0 >> 2, r1 = s1 >> 2;
  const int c0 = (s0 & 3) ^ (r0 & 3) ^ ((r0 >> 2) & 3);
  const int c1 = (s1 & 3) ^ (r1 & 3) ^ ((r1 >> 2) & 3);
  const ushort_t* gA0 = A + (long)(bm * 128 + r0) * K + c0 * 8;
  const ushort_t* gA1 = A + (long)(bm * 128 + r1) * K + c1 * 8;
  const ushort_t* gB0 = Bt + (long)(bn * 128 + r0) * K + c0 * 8;
  const ushort_t* gB1 = Bt + (long)(bn * 128 + r1) * K + c1 * 8;

  const int nk = K >> 5;

  load_lds16(gA0, &As[0][0] + s0 * 8);
  load_lds16(gA1, &As[0][0] + s1 * 8);
  load_lds16(gB0, &Bs[0][0] + s0 * 8);
  load_lds16(gB1, &Bs[0][0] + s1 * 8);

  for (int k = 0; k < nk; ++k) {
    const int cur = k & 1;
    const int nxt = cur ^ 1;
    __syncthreads();

    if (k + 1 < nk) {
      const int off = (k + 1) * 32;
      load_lds16(gA0 + off, &As[nxt][0] + s0 * 8);
      load_lds16(gA1 + off, &As[nxt][0] + s1 * 8);
      load_lds16(gB0 + off, &Bs[nxt][0] + s0 * 8);
      load_lds16(gB1 + off, &Bs[nxt][0] + s1 * 8);
    }

    short8 af[4], bf[4];
#pragma unroll
    for (int i = 0; i < 4; ++i)
      af[i] = *(const short8*)(&As[cur][0] + (wm + i * 16 + l16) * 32 + coff);
#pragma unroll
    for (int j = 0; j < 4; ++j)
      bf[j] = *(const short8*)(&Bs[cur][0] + (wn + j * 16 + l16) * 32 + coff);
#pragma unroll
    for (int i = 0; i < 4; ++i)
#pragma unroll
      for (int j = 0; j < 4; ++j)
        acc[i][j] = __builtin_amdgcn_mfma_f32_16x16x32_bf16(af[i], bf[j], acc[i][j], 0, 0, 0);
  }

#pragma unroll
  for (int i = 0; i < 4; ++i) {
#pragma unroll
    for (int j = 0; j < 4; ++j) {
      const int col = bn * 128 + wn + j * 16 + l16;
      const float bv = bias[col];
      const int row0 = bm * 128 + wm + i * 16 + quad * 4;
#pragma unroll
      for (int r = 0; r < 4; ++r) {
        float v = acc[i][j][r] + bv;
        if (MODE == 0) {
          v = v > 0.0f ? v : 0.0f;
          ((ushort_t*)Cv)[(long)(row0 + r) * N + col] = f2bf(v);
        } else {
          ((float*)Cv)[(long)(row0 + r) * N + col] = v;
        }
      }
    }
  }
}

extern "C" void kernel_launch(void* const* d_in, const int* in_sizes, int n_in,
                              void* d_out, int out_size, void* d_ws, size_t ws_size,
                              hipStream_t stream) {
  const float* h        = (const float*)d_in[0];
  const int*   span_idx = (const int*)d_in[1];
  const float* W1       = (const float*)d_in[2];
  const float* b1       = (const float*)d_in[3];
  const float* W2       = (const float*)d_in[4];
  const float* b2       = (const float*)d_in[5];
  float* out = (float*)d_out;

  // workspace layout (bf16 elements): A | W1T | W2T | Hmid
  ushort_t* A   = (ushort_t*)d_ws;
  ushort_t* W1T = A + (size_t)M_DIM * D_DIM;
  ushort_t* W2T = W1T + (size_t)DFF_DIM * D_DIM;
  ushort_t* Hm  = W2T + (size_t)D_DIM * DFF_DIM;

  // fused prep: both weight transposes + span gather in one launch
  prep<<<2304 + 2304 + M_DIM / 4, 256, 0, stream>>>(W1, W1T, W2, W2T, h, span_idx, A);

  // GEMM1: single-barrier triple-buffer pipeline (128x256 tiles)
  gemm1_p3<<<dim3(M_DIM / 128, DFF_DIM / 256), 512, 0, stream>>>(A, W1T, b1, Hm);

  // GEMM2: Hmid (M x DFF) * W2 (DFF x D) + b2 -> out fp32 (M x D)  [proven]
  gemm_bt<1><<<dim3(M_DIM / 128, D_DIM / 128), 256, 0, stream>>>(
      Hm, W2T, b2, out, M_DIM, D_DIM, DFF_DIM);
}